// Round 10
// baseline (224.601 us; speedup 1.0000x reference)
//
#include <hip/hip_runtime.h>
#include <cmath>

typedef _Float16 half8 __attribute__((ext_vector_type(8)));
typedef _Float16 half4 __attribute__((ext_vector_type(4)));
typedef float floatx4 __attribute__((ext_vector_type(4)));

// Direct global->LDS DMA, 16B per lane. Per-lane global src; LDS dest =
// wave-uniform base + lane*16.
__device__ __forceinline__ void load_lds16(const void* g, void* l) {
  __builtin_amdgcn_global_load_lds((const __attribute__((address_space(1))) void*)g,
                                   (__attribute__((address_space(3))) void*)l, 16, 0, 0);
}

// LDS byte address (32-bit, addrspace(3) numeric value) of a shared pointer.
__device__ __forceinline__ unsigned lds_addr(const void* p) {
  return (unsigned)(unsigned long long)(const __attribute__((address_space(3))) void*)p;
}

// Inline-asm ds_read_b128 (see r4 rationale; kept — equal perf, fewer compiler waits).
__device__ __forceinline__ half8 ds_read128(unsigned addr) {
  half8 r;
  asm volatile("ds_read_b128 %0, %1" : "=v"(r) : "v"(addr));
  return r;
}

// ===== Packed operand format ("MFMA-native") =====
// Matrix [R rows][K halves] (k-contiguous) -> panels of 16 rows. Per panel,
// per 32-half K-block kb, 64 chunks of 16B in order chunk = k16*16 + row16.
// One (panel,kb) block = 1KB contiguous; kb blocks contiguous within a panel.
// chunk_index(row_g,k) = ((row_g>>4)*(K/32) + (k>>5))*64 + ((k>>3)&3)*16 + (row_g&15)

// ---------------- prep: pack X/Wq/Wk rows + transpose-pack Wv ----------------
__global__ void prep_kernel(const float* __restrict__ emb, const float* __restrict__ Wq,
                            const float* __restrict__ Wk, const float* __restrict__ Wv,
                            _Float16* __restrict__ Xp, _Float16* __restrict__ Wqp,
                            _Float16* __restrict__ Wkp, _Float16* __restrict__ Wvtp) {
  int p = blockIdx.x;
  if (p < 640) {
    __shared__ _Float16 lds[16 * 1032];  // padded stride breaks bank aliasing
    const float* src;
    _Float16* dst;
    if (p < 512)      { src = emb + (size_t)p * 16384;        dst = Xp  + (size_t)p * 16384; }
    else if (p < 576) { src = Wq + (size_t)(p - 512) * 16384; dst = Wqp + (size_t)(p - 512) * 16384; }
    else              { src = Wk + (size_t)(p - 576) * 16384; dst = Wkp + (size_t)(p - 576) * 16384; }
    for (int it = 0; it < 16; ++it) {
      int idx = it * 256 + threadIdx.x;  // 4096 float4
      int row = idx >> 8, c4 = idx & 255;
      float4 v = ((const float4*)src)[row * 256 + c4];
      half4 h;
      h[0] = (_Float16)v.x; h[1] = (_Float16)v.y; h[2] = (_Float16)v.z; h[3] = (_Float16)v.w;
      *(half4*)(lds + row * 1032 + c4 * 4) = h;
    }
    __syncthreads();
    for (int it = 0; it < 8; ++it) {
      int c = it * 256 + threadIdx.x;
      int kb = c >> 6, k16 = (c >> 4) & 3, r = c & 15;
      half8 h = *(const half8*)(lds + r * 1032 + kb * 32 + k16 * 8);
      *(half8*)(dst + (size_t)c * 8) = h;  // fully contiguous block write
    }
  } else {
    __shared__ float tile[32][33];
    int q = p - 640;
    int n0 = (q & 31) * 32, k0 = (q >> 5) * 32;
    int c = threadIdx.x & 31, r8 = threadIdx.x >> 5;
    for (int pp = 0; pp < 4; ++pp) {
      int r = pp * 8 + r8;
      tile[r][c] = Wv[(size_t)(k0 + r) * 1024 + n0 + c];
    }
    __syncthreads();
    if (threadIdx.x < 128) {
      int rr = threadIdx.x & 31;         // n (d_out) within tile
      int k16 = (threadIdx.x >> 5) & 3;  // 8-half group within k0
      half8 h;
      for (int kk = 0; kk < 8; ++kk) h[kk] = (_Float16)tile[k16 * 8 + kk][rr];
      int n_row = n0 + rr;
      size_t chunk = ((size_t)(n_row >> 4) * 32 + (k0 >> 5)) * 64 + (k16 << 4) + (n_row & 15);
      *(half8*)(Wvtp + chunk * 8) = h;
    }
  }
}

// ---------------- GEMM core 128x128, BK=32, double-buffered prefetch ---------
// Generalized (r8): explicit lane/wave (two 4-wave groups side by side) +
// kb0 starting K-block offset (split-K). Block-wide __syncthreads inside is
// safe iff both groups call with the SAME kIters (uniform in every caller).
__device__ __forceinline__ void gemm_core_g(int lane, int wave,
                                            const _Float16* __restrict__ Ap, int kbA, int tA0,
                                            const _Float16* __restrict__ Bp, int kbB, int tB0,
                                            int kb0, int kIters, _Float16* sA, _Float16* sB,
                                            floatx4 acc[4][4]) {
  int wm = (wave >> 1) << 6, wn = (wave & 1) << 6;
  const _Float16* gA0 = Ap + ((size_t)(tA0 + 2 * wave) * kbA + kb0) * 512 + lane * 8;
  const _Float16* gA1 = Ap + ((size_t)(tA0 + 2 * wave + 1) * kbA + kb0) * 512 + lane * 8;
  const _Float16* gB0 = Bp + ((size_t)(tB0 + 2 * wave) * kbB + kb0) * 512 + lane * 8;
  const _Float16* gB1 = Bp + ((size_t)(tB0 + 2 * wave + 1) * kbB + kb0) * 512 + lane * 8;
  int ta = wm >> 4, tb = wn >> 4, lo = lane * 8;
  int wo = wave * 1024;  // per-wave slot pair within a buffer

  // prologue: stage K-block kb0 into buffer 0
  load_lds16(gA0, sA + wo);
  load_lds16(gA1, sA + wo + 512);
  load_lds16(gB0, sB + wo);
  load_lds16(gB1, sB + wo + 512);
  __syncthreads();  // implicit vmcnt(0) drain: buffer 0 ready

  int cur = 0;
  for (int kt = 0; kt < kIters; ++kt) {
    if (kt + 1 < kIters) {  // issue next K-block into the other buffer
      size_t kb = (size_t)(kt + 1) * 512;
      int nx = (cur ^ 1) << 12;
      load_lds16(gA0 + kb, sA + nx + wo);
      load_lds16(gA1 + kb, sA + nx + wo + 512);
      load_lds16(gB0 + kb, sB + nx + wo);
      load_lds16(gB1 + kb, sB + nx + wo + 512);
    }
    const _Float16* cA = sA + (cur << 12);
    const _Float16* cB = sB + (cur << 12);
    half8 af[4], bf[4];
    for (int i = 0; i < 4; ++i) af[i] = *(const half8*)(cA + (ta + i) * 512 + lo);
    for (int j = 0; j < 4; ++j) bf[j] = *(const half8*)(cB + (tb + j) * 512 + lo);
    __builtin_amdgcn_s_setprio(1);
    for (int i = 0; i < 4; ++i)
      for (int j = 0; j < 4; ++j)
        acc[i][j] = __builtin_amdgcn_mfma_f32_16x16x32_f16(af[i], bf[j], acc[i][j], 0, 0, 0);
    __builtin_amdgcn_s_setprio(0);
    if (kt + 1 < kIters) {
      __syncthreads();  // drains prefetch vmcnt; all waves done reading cur
      cur ^= 1;
    }
  }
}

__device__ __forceinline__ void gemm_core(const _Float16* __restrict__ Ap, int kbA, int tA0,
                                          const _Float16* __restrict__ Bp, int kbB, int tB0,
                                          int kIters, _Float16* sA, _Float16* sB,
                                          floatx4 acc[4][4]) {
  gemm_core_g(threadIdx.x & 63, threadIdx.x >> 6, Ap, kbA, tA0, Bp, kbB, tB0, 0, kIters, sA, sB, acc);
}

// ---------------- Mt = Wk.Wq^T, packed — r10: intra-block split-K ------------
// mt was pure critical-path-bound: 64 blocks on 256 CUs, duration = one
// block's 32 serial K-iters (~23us). Split-K: 2 groups x 16 iters.
__global__ __launch_bounds__(512, 4) void mt_kernel(
    const _Float16* __restrict__ Wkp, const _Float16* __restrict__ Wqp,
    _Float16* __restrict__ Mtp) {
  __shared__ __align__(16) _Float16 sh2[32768];  // 64 KB: 32 KB per k-group; then xch
  floatx4 acc[4][4];
  for (int i = 0; i < 4; ++i)
    for (int j = 0; j < 4; ++j) acc[i][j] = (floatx4){0.f, 0.f, 0.f, 0.f};
  int m0 = blockIdx.y * 128, n0 = blockIdx.x * 128;  // e', e
  int tid = threadIdx.x;
  int g = tid >> 8, lane = tid & 63, wave = (tid >> 6) & 3;
  _Float16* sA = sh2 + g * 16384;
  _Float16* sB = sA + 8192;
  gemm_core_g(lane, wave, Wkp, 32, m0 >> 4, Wqp, 32, n0 >> 4, g * 16, 16, sA, sB, acc);
  __syncthreads();  // K-loop LDS reads complete in both groups
  floatx4* xch = (floatx4*)sh2;   // 256 thr x 16 floatx4 = 64 KB exactly
  if (g == 1) {
    for (int i = 0; i < 4; ++i)
      for (int j = 0; j < 4; ++j) xch[(tid - 256) * 16 + i * 4 + j] = acc[i][j];
  }
  __syncthreads();
  if (g == 0) {
    for (int i = 0; i < 4; ++i)
      for (int j = 0; j < 4; ++j) acc[i][j] += xch[tid * 16 + i * 4 + j];
    int wm = (wave >> 1) << 6, wn = (wave & 1) << 6;
    int quad = lane >> 4, cl = lane & 15;
    for (int i = 0; i < 4; ++i)
      for (int j = 0; j < 4; ++j)
        for (int rr = 0; rr < 4; ++rr) {
          int row = m0 + wm + i * 16 + quad * 4 + rr;  // e' (packed row dim)
          int col = n0 + wn + j * 16 + cl;             // e  (packed k dim)
          size_t chunk = ((size_t)(row >> 4) * 32 + (col >> 5)) * 64 + (((col >> 3) & 3) << 4) + (row & 15);
          Mtp[chunk * 8 + (col & 7)] = (_Float16)acc[i][j][rr];
        }
  }
}

// ================= proj 256x256, BK=64, 8-wave, 4-phase counted-vmcnt ========
// r5-verified structure (two barriers per phase; LDS-mirror epilogue).
#define NT_PROJ 16

__global__ __launch_bounds__(512, 2) void proj256_kernel(
    const _Float16* __restrict__ Ap, const _Float16* __restrict__ Bp,
    _Float16* __restrict__ XMp, _Float16* __restrict__ Vtp) {
  __shared__ __align__(16) _Float16 sh[65536];  // 128 KB
  int tid = threadIdx.x;
  int lane = tid & 63, w = tid >> 6;
  int wr = w >> 2, wc = w & 3;  // 2M x 4N wave grid; per-wave out 128x64
  // XCD-aware swizzle: 256 blocks, XCD c owns m-tiles [c*4,(c+1)*4) x all n.
  int orig = blockIdx.x;
  int tile = (orig & 7) * 32 + (orig >> 3);
  int mtile = tile >> 3, ntile = tile & 7;
  int tA0 = mtile * 16, tB0 = ntile * 16;

  // Per-wave staging assignments (8 x 1KB chunks per K-step, bijective).
  const _Float16* gB[4];
  int ldsB[4];
  for (int i = 0; i < 4; ++i) {
    int cb = w * 4 + i, pc = cb >> 1, kb = cb & 1;
    gB[i] = Bp + ((size_t)(tB0 + pc) * 32 + kb) * 512 + lane * 8;
    ldsB[i] = 16384 + cb * 512;  // halves, within buffer
  }
  const _Float16* gA[4];
  int ldsA[4];
  {
    int kbw = w & 1, pihi = (w >> 2) * 8, pilo = (w >> 1) & 1;
    for (int q = 0; q < 4; ++q) {
      int p = 2 * q + pilo + pihi;
      gA[q] = Ap + ((size_t)(tA0 + p) * 32 + kbw) * 512 + lane * 8;
      ldsA[q] = (p * 2 + kbw) * 512;
    }
  }

  // 32-bit LDS byte addresses for the asm fragment reads.
  unsigned L = lds_addr(sh);
  unsigned baseA = L + (unsigned)(wr * 16384 + lane * 16);           // A: wr panel group
  unsigned baseB = L + 32768u + (unsigned)(wc * 8192 + lane * 16);   // B: wc panel group

  floatx4 acc[8][4];
  for (int m = 0; m < 8; ++m)
    for (int n = 0; n < 4; ++n) acc[m][n] = (floatx4){0.f, 0.f, 0.f, 0.f};

  // Prologue: fully stage K-steps 0 (buf0) and 1 (buf1), gate K0 with vmcnt(8).
  for (int tt = 0; tt < 2; ++tt) {
    int bo = tt << 15;
    for (int i = 0; i < 4; ++i) load_lds16(gB[i] + (size_t)tt * 1024, sh + bo + ldsB[i]);
    for (int q = 0; q < 4; ++q) load_lds16(gA[q] + (size_t)tt * 1024, sh + bo + ldsA[q]);
  }
  asm volatile("s_waitcnt vmcnt(8)" ::: "memory");
  __builtin_amdgcn_s_barrier();

  half8 bf[4][2];  // B fragments live across the whole K-step
#pragma unroll 2
  for (int t = 0; t < NT_PROJ; ++t) {
    int bo = (t & 1) << 15;                 // halves
    unsigned bob = (unsigned)(t & 1) << 16; // bytes
    unsigned aA = baseA + bob, aB = baseB + bob;
#pragma unroll
    for (int q = 0; q < 4; ++q) {
      // ---- ds_read this phase's fragments (inline asm, untracked) ----
      half8 af[2][2];
      if (q == 0) {
        for (int n = 0; n < 4; ++n)
          for (int kb = 0; kb < 2; ++kb)
            bf[n][kb] = ds_read128(aB + (unsigned)(n * 2048 + kb * 1024));
      }
      for (int mm = 0; mm < 2; ++mm)
        for (int kb = 0; kb < 2; ++kb)
          af[mm][kb] = ds_read128(aA + (unsigned)((2 * q + mm) * 2048 + kb * 1024));
      // ---- staging issue (counted, never drained here) ----
      if (q == 0) {
        if (t >= 1 && t + 1 < NT_PROJ)  // A-q3 for t+1 -> other buffer
          load_lds16(gA[3] + (size_t)(t + 1) * 1024, sh + (bo ^ 32768) + ldsA[3]);
      } else if (q == 1) {
        if (t + 2 < NT_PROJ)
          for (int i = 0; i < 4; ++i)
            load_lds16(gB[i] + (size_t)(t + 2) * 1024, sh + bo + ldsB[i]);
      } else if (q == 2) {
        if (t + 2 < NT_PROJ) {
          load_lds16(gA[0] + (size_t)(t + 2) * 1024, sh + bo + ldsA[0]);
          load_lds16(gA[1] + (size_t)(t + 2) * 1024, sh + bo + ldsA[1]);
        }
      } else {
        // gate t+1's buffer: all its loads done; newest 6 (t+2's B,q0,q1) may fly
        if (t < NT_PROJ - 1) {
          if (t + 2 < NT_PROJ) asm volatile("s_waitcnt vmcnt(6)" ::: "memory");
          else                 asm volatile("s_waitcnt vmcnt(0)" ::: "memory");
        }
        if (t + 2 < NT_PROJ)
          load_lds16(gA[2] + (size_t)(t + 2) * 1024, sh + bo + ldsA[2]);
      }
      // ---- barrier, wait own ds_reads, MFMA cluster ----
      __builtin_amdgcn_s_barrier();
      asm volatile("s_waitcnt lgkmcnt(0)" ::: "memory");
      __builtin_amdgcn_sched_barrier(0);
      __builtin_amdgcn_s_setprio(1);
      for (int mm = 0; mm < 2; ++mm)
        for (int n = 0; n < 4; ++n)
          for (int kb = 0; kb < 2; ++kb)
            acc[2 * q + mm][n] =
                __builtin_amdgcn_mfma_f32_16x16x32_f16(af[mm][kb], bf[n][kb], acc[2 * q + mm][n], 0, 0, 0);
      __builtin_amdgcn_s_setprio(0);
      __builtin_amdgcn_sched_barrier(0);
      __builtin_amdgcn_s_barrier();
    }
  }

  // ---- epilogue: scatter into LDS mirror of the packed tile, then coalesced
  //      copy-out. Local layouts are exact mirrors of the global packed layout
  //      so lhalf-within-group == ghalf-within-group.
  int quad = lane >> 4, cl = lane & 15;
  int which = ntile >> 2;  // 0=XM (cols 0..1023), 1=V (cols 1024..2047)
  for (int m = 0; m < 8; ++m)
    for (int n = 0; n < 4; ++n)
      for (int rr = 0; rr < 4; ++rr) {
        int rl = wr * 128 + m * 16 + quad * 4 + rr;  // row within 256-tile
        int cg = wc * 64 + n * 16 + cl;              // col within 256-tile
        _Float16 val = (_Float16)acc[m][n][rr];
        int lh;
        if (which) {
          // Vt mirror: groups = d-panel (cg>>4) x t-kblock (rl>>5)
          lh = (((cg >> 4) * 8 + (rl >> 5)) << 9) + (((rl >> 3) & 3) << 7) + ((cg & 15) << 3) + (rl & 7);
        } else {
          // XM mirror: groups = t-panel (rl>>4) x col-kblock (cg>>5)
          lh = (((rl >> 4) * 8 + (cg >> 5)) << 9) + (((cg >> 3) & 3) << 7) + ((rl & 15) << 3) + (cg & 7);
        }
        sh[lh] = val;
      }
  __syncthreads();
  int b = mtile >> 3;
  if (which) {
    _Float16* dst = Vtp + (size_t)b * 2097152;
    for (int p = 0; p < 16; ++p) {
      size_t GB = (((size_t)(ntile & 3) * 16 + p) * 64 + (mtile & 7) * 8) * 512;
      *(half8*)(dst + GB + tid * 8) = *(const half8*)(sh + p * 4096 + tid * 8);
    }
  } else {
    _Float16* dst = XMp + (size_t)b * 2097152;
    for (int p = 0; p < 16; ++p) {
      size_t GB = (((size_t)(mtile & 7) * 16 + p) * 32 + (ntile & 3) * 8) * 512;
      *(half8*)(dst + GB + tid * 8) = *(const half8*)(sh + p * 4096 + tid * 8);
    }
  }
}

// ---------------- scores+exp fused: E = exp(XM.X^T/32 - 12), packed ----------
// r10: intra-block split-K (r8-proven mechanism). 512 threads = two 4-wave
// groups, 16 K-iters each (critical path halved); group 1 dumps fp32 acc to
// the 64 KB LDS (exactly 256 thr x 16 floatx4, free after the K-loop),
// group 0 combines then runs the r5-verified exp + packed-mirror + coalesced
// copy-out epilogue. All barriers block-wide (g1 passes through). Row sums
// l_t unchanged: quad-shuffle reduce + one atomicAdd per row (g0 only).
__global__ __launch_bounds__(512, 4) void qke_kernel(
    const _Float16* __restrict__ XMp, const _Float16* __restrict__ Xp,
    _Float16* __restrict__ E, float* __restrict__ lsum) {
  __shared__ __align__(16) _Float16 sh2[32768];  // 64 KB: 2 x 32 KB dbuf; then xch; then E-mirror
  int x = blockIdx.x, b = blockIdx.y;
  int p = (x & 7) * 17 + (x >> 3);  // XCD-contiguous 17-tile chunk (136 = 8*17)
  int ti = 0;
  while ((ti + 1) * (ti + 2) / 2 <= p) ++ti;
  int tj = p - ti * (ti + 1) / 2;
  const _Float16* Ab = XMp + (size_t)b * 2097152;
  const _Float16* Bb = Xp + (size_t)b * 2097152;
  _Float16* Eb = E + (size_t)b * 4194304;
  int tid = threadIdx.x;
  int g = tid >> 8, lane = tid & 63, wave = (tid >> 6) & 3;
  _Float16* sA = sh2 + g * 16384;
  _Float16* sB = sA + 8192;
  floatx4 acc[4][4];
  for (int i = 0; i < 4; ++i)
    for (int j = 0; j < 4; ++j) acc[i][j] = (floatx4){0.f, 0.f, 0.f, 0.f};
  gemm_core_g(lane, wave, Ab, 32, ti * 8, Bb, 32, tj * 8, g * 16, 16, sA, sB, acc);
  __syncthreads();  // K-loop LDS reads complete in both groups
  floatx4* xch = (floatx4*)sh2;   // 256 thr x 16 floatx4 = 64 KB exactly
  if (g == 1) {
    for (int i = 0; i < 4; ++i)
      for (int j = 0; j < 4; ++j) xch[(tid - 256) * 16 + i * 4 + j] = acc[i][j];
  }
  __syncthreads();
  if (g == 0) {
    for (int i = 0; i < 4; ++i)
      for (int j = 0; j < 4; ++j) acc[i][j] += xch[tid * 16 + i * 4 + j];
  }
  __syncthreads();  // all xch reads done before mirror overwrites the region
  int wm = (wave >> 1) << 6, wn = (wave & 1) << 6;
  int quad = lane >> 4, cl = lane & 15;
  float rs[4][4];
  for (int i = 0; i < 4; ++i)
    for (int rr = 0; rr < 4; ++rr) rs[i][rr] = 0.f;
  if (g == 0) {
    for (int i = 0; i < 4; ++i)
      for (int j = 0; j < 4; ++j)
        for (int rr = 0; rr < 4; ++rr) {
          int rl = wm + i * 16 + quad * 4 + rr;  // row within 128-tile
          int cg = wn + j * 16 + cl;             // col within 128-tile
          int row = ti * 128 + rl, col = tj * 128 + cg;
          float e = 0.f;
          if (col <= row) e = __expf(acc[i][j][rr] * 0.03125f - 12.0f);
          _Float16 eh = (_Float16)e;
          rs[i][rr] += (float)eh;  // sum the fp16-rounded value pv will see
          // LDS mirror of packed E tile: group = panel(rl>>4) x kblock(cg>>5)
          int lh = (((rl >> 4) * 4 + (cg >> 5)) << 9) + (((cg >> 3) & 3) << 7) + ((rl & 15) << 3) + (cg & 7);
          sh2[lh] = eh;
        }
  }
  __syncthreads();
  if (g == 0) {
    // coalesced copy-out: 8 panel-groups x 2048 halves (4 KB contiguous global)
    for (int pp = 0; pp < 8; ++pp) {
      size_t GB = ((size_t)(ti * 8 + pp) * 64 + tj * 4) * 512;
      *(half8*)(Eb + GB + tid * 8) = *(const half8*)(sh2 + pp * 2048 + tid * 8);
    }
    // reduce over the 16 cl lanes within each quad (rows are cl-invariant)
    float* lb = lsum + (size_t)b * 2048;
    for (int i = 0; i < 4; ++i)
      for (int rr = 0; rr < 4; ++rr) {
        float v = rs[i][rr];
        v += __shfl_xor(v, 1, 64);
        v += __shfl_xor(v, 2, 64);
        v += __shfl_xor(v, 4, 64);
        v += __shfl_xor(v, 8, 64);
        if (cl == 0) atomicAdd(lb + ti * 128 + wm + i * 16 + quad * 4 + rr, v);
      }
  }
}

// ---------------- O^T = V.E^T / l, 128x128 tiles, fp32 out -------------------
// r8/r9-verified intra-block split-K (critical path 64 -> 32 iters).
__global__ __launch_bounds__(512, 4) void pv_kernel(
    const _Float16* __restrict__ E, const _Float16* __restrict__ Vtp,
    const float* __restrict__ lsum, float* __restrict__ out) {
  __shared__ __align__(16) _Float16 sh2[32768];  // 64 KB: 32 KB per k-group
  // XCD-aware bijective swizzle over the full 512-block grid.
  int orig = blockIdx.x + 8 * (blockIdx.y + 16 * blockIdx.z);
  int logical = (orig & 7) * 64 + (orig >> 3);
  int n0 = (logical & 7) * 128;   // d-tile base
  int rest = logical >> 3;        // 0..63
  int y = rest & 15, b = rest >> 4;
  int ti = (y & 1) ? (15 - (y >> 1)) : (y >> 1);  // zigzag (harmless now)
  const _Float16* Pb = E + (size_t)b * 4194304;
  const _Float16* Vb = Vtp + (size_t)b * 2097152;
  int tid = threadIdx.x;
  int g = tid >> 8, lane = tid & 63, wave = (tid >> 6) & 3;
  int half = (ti + 1) * 2;        // K-iters per group (equal for g=0,1)
  _Float16* sA = sh2 + g * 16384;
  _Float16* sB = sA + 8192;
  floatx4 acc[4][4];
  for (int i = 0; i < 4; ++i)
    for (int j = 0; j < 4; ++j) acc[i][j] = (floatx4){0.f, 0.f, 0.f, 0.f};
  // A = Vt (d rows, k=s), B = E (t rows, k=s); group g covers kb [g*half, (g+1)*half)
  gemm_core_g(lane, wave, Vb, 64, n0 >> 4, Pb, 64, ti * 8, g * half, half, sA, sB, acc);
  __syncthreads();  // K-loop LDS reads complete in both groups
  floatx4* xch = (floatx4*)sh2;   // 256 thr x 16 floatx4 = 64 KB exactly
  if (g == 1) {
    for (int i = 0; i < 4; ++i)
      for (int j = 0; j < 4; ++j) xch[(tid - 256) * 16 + i * 4 + j] = acc[i][j];
  }
  __syncthreads();
  if (g == 0) {
    int wm = (wave >> 1) << 6, wn = (wave & 1) << 6;
    int quad = lane >> 4, cl = lane & 15;
    const float* lb = lsum + (size_t)b * 2048;
    for (int j = 0; j < 4; ++j) {
      int t = ti * 128 + wn + j * 16 + cl;  // col dim = t
      float inv = 1.0f / lb[t];
      float* orow = out + ((size_t)b * 2048 + t) * 1024;
      for (int i = 0; i < 4; ++i) {
        floatx4 a = acc[i][j];
        floatx4 p = xch[tid * 16 + i * 4 + j];
        int d0 = n0 + wm + i * 16 + quad * 4;  // row dim = d, 4 consecutive
        float4 v;
        v.x = rintf((a[0] + p[0]) * inv * 10000.f) * 1e-4f;
        v.y = rintf((a[1] + p[1]) * inv * 10000.f) * 1e-4f;
        v.z = rintf((a[2] + p[2]) * inv * 10000.f) * 1e-4f;
        v.w = rintf((a[3] + p[3]) * inv * 10000.f) * 1e-4f;
        *(float4*)(orow + d0) = v;
      }
    }
  }
}

extern "C" void kernel_launch(void* const* d_in, const int* in_sizes, int n_in,
                              void* d_out, int out_size, void* d_ws, size_t ws_size,
                              hipStream_t stream) {
  const float* emb = (const float*)d_in[0];
  const float* Wk = (const float*)d_in[1];
  const float* Wq = (const float*)d_in[2];
  const float* Wv = (const float*)d_in[3];
  float* out = (float*)d_out;

  _Float16* ws = (_Float16*)d_ws;
  _Float16* Xp   = ws;                           //  8M halves (packed X)
  _Float16* Wqp  = Xp + (size_t)8192 * 1024;     //  1M (packed Wq rows, k=f)
  _Float16* Wkp  = Wqp + (size_t)1024 * 1024;    //  1M (packed Wk rows, k=f)
  _Float16* Mtp  = Wkp + (size_t)1024 * 1024;    //  1M (packed Wk.Wq^T) — proj B panels 0..63
  _Float16* Wvtp = Mtp + (size_t)1024 * 1024;    //  1M (packed Wv^T)   — proj B panels 64..127
  _Float16* XMp  = Wvtp + (size_t)1024 * 1024;   //  8M (packed XM)
  _Float16* Vtp  = XMp + (size_t)8192 * 1024;    //  8M (packed Vt[d][t])
  _Float16* Ebuf = Vtp + (size_t)8192 * 1024;    // 16M (packed exp-scores E)
  float* lsum    = (float*)(Ebuf + (size_t)16 * 1024 * 1024);  // 8K fp32 row sums

  // zero the row-sum accumulator (ws is poisoned 0xAA before every launch)
  hipMemsetAsync(lsum, 0, 4 * 2048 * sizeof(float), stream);
  prep_kernel<<<1664, 256, 0, stream>>>(emb, Wq, Wk, Wv, Xp, Wqp, Wkp, Wvtp);
  mt_kernel<<<dim3(8, 8), 512, 0, stream>>>(Wkp, Wqp, Mtp);
  proj256_kernel<<<256, 512, 0, stream>>>(Xp, Mtp, XMp, Vtp);
  qke_kernel<<<dim3(136, 4), 512, 0, stream>>>(XMp, Xp, Ebuf, lsum);
  pv_kernel<<<dim3(8, 16, 4), 512, 0, stream>>>(Ebuf, Vtp, lsum, out);
}

// Round 11
// 200.691 us; speedup vs baseline: 1.1191x; 1.1191x over previous
//
#include <hip/hip_runtime.h>
#include <cmath>

typedef _Float16 half8 __attribute__((ext_vector_type(8)));
typedef _Float16 half4 __attribute__((ext_vector_type(4)));
typedef float floatx4 __attribute__((ext_vector_type(4)));

// Direct global->LDS DMA, 16B per lane. Per-lane global src; LDS dest =
// wave-uniform base + lane*16.
__device__ __forceinline__ void load_lds16(const void* g, void* l) {
  __builtin_amdgcn_global_load_lds((const __attribute__((address_space(1))) void*)g,
                                   (__attribute__((address_space(3))) void*)l, 16, 0, 0);
}

// LDS byte address (32-bit, addrspace(3) numeric value) of a shared pointer.
__device__ __forceinline__ unsigned lds_addr(const void* p) {
  return (unsigned)(unsigned long long)(const __attribute__((address_space(3))) void*)p;
}

// Inline-asm ds_read_b128 (see r4 rationale; kept — equal perf, fewer compiler waits).
__device__ __forceinline__ half8 ds_read128(unsigned addr) {
  half8 r;
  asm volatile("ds_read_b128 %0, %1" : "=v"(r) : "v"(addr));
  return r;
}

// ===== Packed operand format ("MFMA-native") =====
// Matrix [R rows][K halves] (k-contiguous) -> panels of 16 rows. Per panel,
// per 32-half K-block kb, 64 chunks of 16B in order chunk = k16*16 + row16.
// One (panel,kb) block = 1KB contiguous; kb blocks contiguous within a panel.
// chunk_index(row_g,k) = ((row_g>>4)*(K/32) + (k>>5))*64 + ((k>>3)&3)*16 + (row_g&15)

// ---------------- prep: pack X/Wq/Wk rows + transpose-pack Wv ----------------
__global__ void prep_kernel(const float* __restrict__ emb, const float* __restrict__ Wq,
                            const float* __restrict__ Wk, const float* __restrict__ Wv,
                            _Float16* __restrict__ Xp, _Float16* __restrict__ Wqp,
                            _Float16* __restrict__ Wkp, _Float16* __restrict__ Wvtp) {
  int p = blockIdx.x;
  if (p < 640) {
    __shared__ _Float16 lds[16 * 1032];  // padded stride breaks bank aliasing
    const float* src;
    _Float16* dst;
    if (p < 512)      { src = emb + (size_t)p * 16384;        dst = Xp  + (size_t)p * 16384; }
    else if (p < 576) { src = Wq + (size_t)(p - 512) * 16384; dst = Wqp + (size_t)(p - 512) * 16384; }
    else              { src = Wk + (size_t)(p - 576) * 16384; dst = Wkp + (size_t)(p - 576) * 16384; }
    for (int it = 0; it < 16; ++it) {
      int idx = it * 256 + threadIdx.x;  // 4096 float4
      int row = idx >> 8, c4 = idx & 255;
      float4 v = ((const float4*)src)[row * 256 + c4];
      half4 h;
      h[0] = (_Float16)v.x; h[1] = (_Float16)v.y; h[2] = (_Float16)v.z; h[3] = (_Float16)v.w;
      *(half4*)(lds + row * 1032 + c4 * 4) = h;
    }
    __syncthreads();
    for (int it = 0; it < 8; ++it) {
      int c = it * 256 + threadIdx.x;
      int kb = c >> 6, k16 = (c >> 4) & 3, r = c & 15;
      half8 h = *(const half8*)(lds + r * 1032 + kb * 32 + k16 * 8);
      *(half8*)(dst + (size_t)c * 8) = h;  // fully contiguous block write
    }
  } else {
    __shared__ float tile[32][33];
    int q = p - 640;
    int n0 = (q & 31) * 32, k0 = (q >> 5) * 32;
    int c = threadIdx.x & 31, r8 = threadIdx.x >> 5;
    for (int pp = 0; pp < 4; ++pp) {
      int r = pp * 8 + r8;
      tile[r][c] = Wv[(size_t)(k0 + r) * 1024 + n0 + c];
    }
    __syncthreads();
    if (threadIdx.x < 128) {
      int rr = threadIdx.x & 31;         // n (d_out) within tile
      int k16 = (threadIdx.x >> 5) & 3;  // 8-half group within k0
      half8 h;
      for (int kk = 0; kk < 8; ++kk) h[kk] = (_Float16)tile[k16 * 8 + kk][rr];
      int n_row = n0 + rr;
      size_t chunk = ((size_t)(n_row >> 4) * 32 + (k0 >> 5)) * 64 + (k16 << 4) + (n_row & 15);
      *(half8*)(Wvtp + chunk * 8) = h;
    }
  }
}

// ---------------- GEMM core 128x128, BK=32, double-buffered prefetch ---------
// Generalized (r8): explicit lane/wave (two 4-wave groups side by side) +
// kb0 starting K-block offset (split-K). Block-wide __syncthreads inside is
// safe iff both groups call with the SAME kIters (uniform in every caller).
__device__ __forceinline__ void gemm_core_g(int lane, int wave,
                                            const _Float16* __restrict__ Ap, int kbA, int tA0,
                                            const _Float16* __restrict__ Bp, int kbB, int tB0,
                                            int kb0, int kIters, _Float16* sA, _Float16* sB,
                                            floatx4 acc[4][4]) {
  int wm = (wave >> 1) << 6, wn = (wave & 1) << 6;
  const _Float16* gA0 = Ap + ((size_t)(tA0 + 2 * wave) * kbA + kb0) * 512 + lane * 8;
  const _Float16* gA1 = Ap + ((size_t)(tA0 + 2 * wave + 1) * kbA + kb0) * 512 + lane * 8;
  const _Float16* gB0 = Bp + ((size_t)(tB0 + 2 * wave) * kbB + kb0) * 512 + lane * 8;
  const _Float16* gB1 = Bp + ((size_t)(tB0 + 2 * wave + 1) * kbB + kb0) * 512 + lane * 8;
  int ta = wm >> 4, tb = wn >> 4, lo = lane * 8;
  int wo = wave * 1024;  // per-wave slot pair within a buffer

  // prologue: stage K-block kb0 into buffer 0
  load_lds16(gA0, sA + wo);
  load_lds16(gA1, sA + wo + 512);
  load_lds16(gB0, sB + wo);
  load_lds16(gB1, sB + wo + 512);
  __syncthreads();  // implicit vmcnt(0) drain: buffer 0 ready

  int cur = 0;
  for (int kt = 0; kt < kIters; ++kt) {
    if (kt + 1 < kIters) {  // issue next K-block into the other buffer
      size_t kb = (size_t)(kt + 1) * 512;
      int nx = (cur ^ 1) << 12;
      load_lds16(gA0 + kb, sA + nx + wo);
      load_lds16(gA1 + kb, sA + nx + wo + 512);
      load_lds16(gB0 + kb, sB + nx + wo);
      load_lds16(gB1 + kb, sB + nx + wo + 512);
    }
    const _Float16* cA = sA + (cur << 12);
    const _Float16* cB = sB + (cur << 12);
    half8 af[4], bf[4];
    for (int i = 0; i < 4; ++i) af[i] = *(const half8*)(cA + (ta + i) * 512 + lo);
    for (int j = 0; j < 4; ++j) bf[j] = *(const half8*)(cB + (tb + j) * 512 + lo);
    __builtin_amdgcn_s_setprio(1);
    for (int i = 0; i < 4; ++i)
      for (int j = 0; j < 4; ++j)
        acc[i][j] = __builtin_amdgcn_mfma_f32_16x16x32_f16(af[i], bf[j], acc[i][j], 0, 0, 0);
    __builtin_amdgcn_s_setprio(0);
    if (kt + 1 < kIters) {
      __syncthreads();  // drains prefetch vmcnt; all waves done reading cur
      cur ^= 1;
    }
  }
}

__device__ __forceinline__ void gemm_core(const _Float16* __restrict__ Ap, int kbA, int tA0,
                                          const _Float16* __restrict__ Bp, int kbB, int tB0,
                                          int kIters, _Float16* sA, _Float16* sB,
                                          floatx4 acc[4][4]) {
  gemm_core_g(threadIdx.x & 63, threadIdx.x >> 6, Ap, kbA, tA0, Bp, kbB, tB0, 0, kIters, sA, sB, acc);
}

// ---------------- Mt = Wk.Wq^T, packed — split-K (r10) + xch fix (r11) -------
// mt is critical-path-bound: 64 blocks on 256 CUs. Split-K: 2 groups x 16
// iters. r11: exchange layout transposed to xch[slot*256 + tid] so
// consecutive lanes touch consecutive 16B (2-way alias = free); r10's
// xch[tid*16+slot] was a 64-way bank conflict (256B lane stride).
__global__ __launch_bounds__(512, 4) void mt_kernel(
    const _Float16* __restrict__ Wkp, const _Float16* __restrict__ Wqp,
    _Float16* __restrict__ Mtp) {
  __shared__ __align__(16) _Float16 sh2[32768];  // 64 KB: 32 KB per k-group; then xch
  floatx4 acc[4][4];
  for (int i = 0; i < 4; ++i)
    for (int j = 0; j < 4; ++j) acc[i][j] = (floatx4){0.f, 0.f, 0.f, 0.f};
  int m0 = blockIdx.y * 128, n0 = blockIdx.x * 128;  // e', e
  int tid = threadIdx.x;
  int g = tid >> 8, lane = tid & 63, wave = (tid >> 6) & 3;
  _Float16* sA = sh2 + g * 16384;
  _Float16* sB = sA + 8192;
  gemm_core_g(lane, wave, Wkp, 32, m0 >> 4, Wqp, 32, n0 >> 4, g * 16, 16, sA, sB, acc);
  __syncthreads();  // K-loop LDS reads complete in both groups
  floatx4* xch = (floatx4*)sh2;   // 16 slots x 256 thr x 16B = 64 KB exactly
  if (g == 1) {
    for (int i = 0; i < 4; ++i)
      for (int j = 0; j < 4; ++j) xch[(i * 4 + j) * 256 + (tid - 256)] = acc[i][j];
  }
  __syncthreads();
  if (g == 0) {
    for (int i = 0; i < 4; ++i)
      for (int j = 0; j < 4; ++j) acc[i][j] += xch[(i * 4 + j) * 256 + tid];
    int wm = (wave >> 1) << 6, wn = (wave & 1) << 6;
    int quad = lane >> 4, cl = lane & 15;
    for (int i = 0; i < 4; ++i)
      for (int j = 0; j < 4; ++j)
        for (int rr = 0; rr < 4; ++rr) {
          int row = m0 + wm + i * 16 + quad * 4 + rr;  // e' (packed row dim)
          int col = n0 + wn + j * 16 + cl;             // e  (packed k dim)
          size_t chunk = ((size_t)(row >> 4) * 32 + (col >> 5)) * 64 + (((col >> 3) & 3) << 4) + (row & 15);
          Mtp[chunk * 8 + (col & 7)] = (_Float16)acc[i][j][rr];
        }
  }
}

// ================= proj 256x256, BK=64, 8-wave, 4-phase counted-vmcnt ========
// r5-verified structure (two barriers per phase; LDS-mirror epilogue).
#define NT_PROJ 16

__global__ __launch_bounds__(512, 2) void proj256_kernel(
    const _Float16* __restrict__ Ap, const _Float16* __restrict__ Bp,
    _Float16* __restrict__ XMp, _Float16* __restrict__ Vtp) {
  __shared__ __align__(16) _Float16 sh[65536];  // 128 KB
  int tid = threadIdx.x;
  int lane = tid & 63, w = tid >> 6;
  int wr = w >> 2, wc = w & 3;  // 2M x 4N wave grid; per-wave out 128x64
  // XCD-aware swizzle: 256 blocks, XCD c owns m-tiles [c*4,(c+1)*4) x all n.
  int orig = blockIdx.x;
  int tile = (orig & 7) * 32 + (orig >> 3);
  int mtile = tile >> 3, ntile = tile & 7;
  int tA0 = mtile * 16, tB0 = ntile * 16;

  // Per-wave staging assignments (8 x 1KB chunks per K-step, bijective).
  const _Float16* gB[4];
  int ldsB[4];
  for (int i = 0; i < 4; ++i) {
    int cb = w * 4 + i, pc = cb >> 1, kb = cb & 1;
    gB[i] = Bp + ((size_t)(tB0 + pc) * 32 + kb) * 512 + lane * 8;
    ldsB[i] = 16384 + cb * 512;  // halves, within buffer
  }
  const _Float16* gA[4];
  int ldsA[4];
  {
    int kbw = w & 1, pihi = (w >> 2) * 8, pilo = (w >> 1) & 1;
    for (int q = 0; q < 4; ++q) {
      int p = 2 * q + pilo + pihi;
      gA[q] = Ap + ((size_t)(tA0 + p) * 32 + kbw) * 512 + lane * 8;
      ldsA[q] = (p * 2 + kbw) * 512;
    }
  }

  // 32-bit LDS byte addresses for the asm fragment reads.
  unsigned L = lds_addr(sh);
  unsigned baseA = L + (unsigned)(wr * 16384 + lane * 16);           // A: wr panel group
  unsigned baseB = L + 32768u + (unsigned)(wc * 8192 + lane * 16);   // B: wc panel group

  floatx4 acc[8][4];
  for (int m = 0; m < 8; ++m)
    for (int n = 0; n < 4; ++n) acc[m][n] = (floatx4){0.f, 0.f, 0.f, 0.f};

  // Prologue: fully stage K-steps 0 (buf0) and 1 (buf1), gate K0 with vmcnt(8).
  for (int tt = 0; tt < 2; ++tt) {
    int bo = tt << 15;
    for (int i = 0; i < 4; ++i) load_lds16(gB[i] + (size_t)tt * 1024, sh + bo + ldsB[i]);
    for (int q = 0; q < 4; ++q) load_lds16(gA[q] + (size_t)tt * 1024, sh + bo + ldsA[q]);
  }
  asm volatile("s_waitcnt vmcnt(8)" ::: "memory");
  __builtin_amdgcn_s_barrier();

  half8 bf[4][2];  // B fragments live across the whole K-step
#pragma unroll 2
  for (int t = 0; t < NT_PROJ; ++t) {
    int bo = (t & 1) << 15;                 // halves
    unsigned bob = (unsigned)(t & 1) << 16; // bytes
    unsigned aA = baseA + bob, aB = baseB + bob;
#pragma unroll
    for (int q = 0; q < 4; ++q) {
      // ---- ds_read this phase's fragments (inline asm, untracked) ----
      half8 af[2][2];
      if (q == 0) {
        for (int n = 0; n < 4; ++n)
          for (int kb = 0; kb < 2; ++kb)
            bf[n][kb] = ds_read128(aB + (unsigned)(n * 2048 + kb * 1024));
      }
      for (int mm = 0; mm < 2; ++mm)
        for (int kb = 0; kb < 2; ++kb)
          af[mm][kb] = ds_read128(aA + (unsigned)((2 * q + mm) * 2048 + kb * 1024));
      // ---- staging issue (counted, never drained here) ----
      if (q == 0) {
        if (t >= 1 && t + 1 < NT_PROJ)  // A-q3 for t+1 -> other buffer
          load_lds16(gA[3] + (size_t)(t + 1) * 1024, sh + (bo ^ 32768) + ldsA[3]);
      } else if (q == 1) {
        if (t + 2 < NT_PROJ)
          for (int i = 0; i < 4; ++i)
            load_lds16(gB[i] + (size_t)(t + 2) * 1024, sh + bo + ldsB[i]);
      } else if (q == 2) {
        if (t + 2 < NT_PROJ) {
          load_lds16(gA[0] + (size_t)(t + 2) * 1024, sh + bo + ldsA[0]);
          load_lds16(gA[1] + (size_t)(t + 2) * 1024, sh + bo + ldsA[1]);
        }
      } else {
        // gate t+1's buffer: all its loads done; newest 6 (t+2's B,q0,q1) may fly
        if (t < NT_PROJ - 1) {
          if (t + 2 < NT_PROJ) asm volatile("s_waitcnt vmcnt(6)" ::: "memory");
          else                 asm volatile("s_waitcnt vmcnt(0)" ::: "memory");
        }
        if (t + 2 < NT_PROJ)
          load_lds16(gA[2] + (size_t)(t + 2) * 1024, sh + bo + ldsA[2]);
      }
      // ---- barrier, wait own ds_reads, MFMA cluster ----
      __builtin_amdgcn_s_barrier();
      asm volatile("s_waitcnt lgkmcnt(0)" ::: "memory");
      __builtin_amdgcn_sched_barrier(0);
      __builtin_amdgcn_s_setprio(1);
      for (int mm = 0; mm < 2; ++mm)
        for (int n = 0; n < 4; ++n)
          for (int kb = 0; kb < 2; ++kb)
            acc[2 * q + mm][n] =
                __builtin_amdgcn_mfma_f32_16x16x32_f16(af[mm][kb], bf[n][kb], acc[2 * q + mm][n], 0, 0, 0);
      __builtin_amdgcn_s_setprio(0);
      __builtin_amdgcn_sched_barrier(0);
      __builtin_amdgcn_s_barrier();
    }
  }

  // ---- epilogue: scatter into LDS mirror of the packed tile, then coalesced
  //      copy-out. Local layouts are exact mirrors of the global packed layout
  //      so lhalf-within-group == ghalf-within-group.
  int quad = lane >> 4, cl = lane & 15;
  int which = ntile >> 2;  // 0=XM (cols 0..1023), 1=V (cols 1024..2047)
  for (int m = 0; m < 8; ++m)
    for (int n = 0; n < 4; ++n)
      for (int rr = 0; rr < 4; ++rr) {
        int rl = wr * 128 + m * 16 + quad * 4 + rr;  // row within 256-tile
        int cg = wc * 64 + n * 16 + cl;              // col within 256-tile
        _Float16 val = (_Float16)acc[m][n][rr];
        int lh;
        if (which) {
          // Vt mirror: groups = d-panel (cg>>4) x t-kblock (rl>>5)
          lh = (((cg >> 4) * 8 + (rl >> 5)) << 9) + (((rl >> 3) & 3) << 7) + ((cg & 15) << 3) + (rl & 7);
        } else {
          // XM mirror: groups = t-panel (rl>>4) x col-kblock (cg>>5)
          lh = (((rl >> 4) * 8 + (cg >> 5)) << 9) + (((cg >> 3) & 3) << 7) + ((rl & 15) << 3) + (cg & 7);
        }
        sh[lh] = val;
      }
  __syncthreads();
  int b = mtile >> 3;
  if (which) {
    _Float16* dst = Vtp + (size_t)b * 2097152;
    for (int p = 0; p < 16; ++p) {
      size_t GB = (((size_t)(ntile & 3) * 16 + p) * 64 + (mtile & 7) * 8) * 512;
      *(half8*)(dst + GB + tid * 8) = *(const half8*)(sh + p * 4096 + tid * 8);
    }
  } else {
    _Float16* dst = XMp + (size_t)b * 2097152;
    for (int p = 0; p < 16; ++p) {
      size_t GB = (((size_t)(mtile & 7) * 16 + p) * 32 + (ntile & 3) * 8) * 512;
      *(half8*)(dst + GB + tid * 8) = *(const half8*)(sh + p * 4096 + tid * 8);
    }
  }
}

// ---------------- scores+exp fused: E = exp(XM.X^T/32 - 12), packed ----------
// r11: EXACT r5 revert (256 threads, no split-K). qke is throughput-bound
// (544 blocks ~ 2.1/CU gives inter-block overlap); r10's split-K regressed
// it 45 -> 48.6us with 4.3M bank conflicts. Row max analytically bounded ->
// fixed shift 12; masked entries store 0; l_t via quad-shuffle + atomicAdd.
// E tile staged in LDS (packed-mirror) -> coalesced b128 stores.
__global__ void qke_kernel(const _Float16* __restrict__ XMp, const _Float16* __restrict__ Xp,
                           _Float16* __restrict__ E, float* __restrict__ lsum) {
  __shared__ __align__(16) _Float16 sh[16384];  // GEMM dbuf, then E-tile mirror
  int x = blockIdx.x, b = blockIdx.y;
  int p = (x & 7) * 17 + (x >> 3);  // XCD-contiguous 17-tile chunk (136 = 8*17)
  int ti = 0;
  while ((ti + 1) * (ti + 2) / 2 <= p) ++ti;
  int tj = p - ti * (ti + 1) / 2;
  const _Float16* Ab = XMp + (size_t)b * 2097152;
  const _Float16* Bb = Xp + (size_t)b * 2097152;
  _Float16* Eb = E + (size_t)b * 4194304;
  floatx4 acc[4][4];
  for (int i = 0; i < 4; ++i)
    for (int j = 0; j < 4; ++j) acc[i][j] = (floatx4){0.f, 0.f, 0.f, 0.f};
  gemm_core(Ab, 32, ti * 8, Bb, 32, tj * 8, 32, sh, sh + 8192, acc);
  int lane = threadIdx.x & 63, wave = threadIdx.x >> 6;
  int wm = (wave >> 1) << 6, wn = (wave & 1) << 6;
  int quad = lane >> 4, cl = lane & 15;
  float rs[4][4];
  for (int i = 0; i < 4; ++i)
    for (int rr = 0; rr < 4; ++rr) rs[i][rr] = 0.f;
  __syncthreads();  // all waves done with GEMM LDS reads before overwrite
  for (int i = 0; i < 4; ++i)
    for (int j = 0; j < 4; ++j)
      for (int rr = 0; rr < 4; ++rr) {
        int rl = wm + i * 16 + quad * 4 + rr;  // row within 128-tile
        int cg = wn + j * 16 + cl;             // col within 128-tile
        int row = ti * 128 + rl, col = tj * 128 + cg;
        float e = 0.f;
        if (col <= row) e = __expf(acc[i][j][rr] * 0.03125f - 12.0f);
        _Float16 eh = (_Float16)e;
        rs[i][rr] += (float)eh;  // sum the fp16-rounded value pv will see
        // LDS mirror of packed E tile: group = panel(rl>>4) x kblock(cg>>5)
        int lh = (((rl >> 4) * 4 + (cg >> 5)) << 9) + (((cg >> 3) & 3) << 7) + ((rl & 15) << 3) + (cg & 7);
        sh[lh] = eh;
      }
  __syncthreads();
  // coalesced copy-out: 8 panel-groups x 2048 halves (4 KB contiguous global)
  for (int pp = 0; pp < 8; ++pp) {
    size_t GB = ((size_t)(ti * 8 + pp) * 64 + tj * 4) * 512;
    *(half8*)(Eb + GB + threadIdx.x * 8) = *(const half8*)(sh + pp * 2048 + threadIdx.x * 8);
  }
  // reduce over the 16 cl lanes within each quad (rows are cl-invariant)
  float* lb = lsum + (size_t)b * 2048;
  for (int i = 0; i < 4; ++i)
    for (int rr = 0; rr < 4; ++rr) {
      float v = rs[i][rr];
      v += __shfl_xor(v, 1, 64);
      v += __shfl_xor(v, 2, 64);
      v += __shfl_xor(v, 4, 64);
      v += __shfl_xor(v, 8, 64);
      if (cl == 0) atomicAdd(lb + ti * 128 + wm + i * 16 + quad * 4 + rr, v);
    }
}

// ---------------- O^T = V.E^T / l, 128x128 tiles, fp32 out -------------------
// r8/r9-verified intra-block split-K (critical path 64 -> 32 iters).
// r11: xch layout transposed (see mt) to kill the 64-way bank conflict.
__global__ __launch_bounds__(512, 4) void pv_kernel(
    const _Float16* __restrict__ E, const _Float16* __restrict__ Vtp,
    const float* __restrict__ lsum, float* __restrict__ out) {
  __shared__ __align__(16) _Float16 sh2[32768];  // 64 KB: 32 KB per k-group
  // XCD-aware bijective swizzle over the full 512-block grid.
  int orig = blockIdx.x + 8 * (blockIdx.y + 16 * blockIdx.z);
  int logical = (orig & 7) * 64 + (orig >> 3);
  int n0 = (logical & 7) * 128;   // d-tile base
  int rest = logical >> 3;        // 0..63
  int y = rest & 15, b = rest >> 4;
  int ti = (y & 1) ? (15 - (y >> 1)) : (y >> 1);  // zigzag (harmless now)
  const _Float16* Pb = E + (size_t)b * 4194304;
  const _Float16* Vb = Vtp + (size_t)b * 2097152;
  int tid = threadIdx.x;
  int g = tid >> 8, lane = tid & 63, wave = (tid >> 6) & 3;
  int half = (ti + 1) * 2;        // K-iters per group (equal for g=0,1)
  _Float16* sA = sh2 + g * 16384;
  _Float16* sB = sA + 8192;
  floatx4 acc[4][4];
  for (int i = 0; i < 4; ++i)
    for (int j = 0; j < 4; ++j) acc[i][j] = (floatx4){0.f, 0.f, 0.f, 0.f};
  // A = Vt (d rows, k=s), B = E (t rows, k=s); group g covers kb [g*half, (g+1)*half)
  gemm_core_g(lane, wave, Vb, 64, n0 >> 4, Pb, 64, ti * 8, g * half, half, sA, sB, acc);
  __syncthreads();  // K-loop LDS reads complete in both groups
  floatx4* xch = (floatx4*)sh2;   // 16 slots x 256 thr x 16B = 64 KB exactly
  if (g == 1) {
    for (int i = 0; i < 4; ++i)
      for (int j = 0; j < 4; ++j) xch[(i * 4 + j) * 256 + (tid - 256)] = acc[i][j];
  }
  __syncthreads();
  if (g == 0) {
    int wm = (wave >> 1) << 6, wn = (wave & 1) << 6;
    int quad = lane >> 4, cl = lane & 15;
    const float* lb = lsum + (size_t)b * 2048;
    for (int j = 0; j < 4; ++j) {
      int t = ti * 128 + wn + j * 16 + cl;  // col dim = t
      float inv = 1.0f / lb[t];
      float* orow = out + ((size_t)b * 2048 + t) * 1024;
      for (int i = 0; i < 4; ++i) {
        floatx4 a = acc[i][j];
        floatx4 p = xch[(i * 4 + j) * 256 + tid];
        int d0 = n0 + wm + i * 16 + quad * 4;  // row dim = d, 4 consecutive
        float4 v;
        v.x = rintf((a[0] + p[0]) * inv * 10000.f) * 1e-4f;
        v.y = rintf((a[1] + p[1]) * inv * 10000.f) * 1e-4f;
        v.z = rintf((a[2] + p[2]) * inv * 10000.f) * 1e-4f;
        v.w = rintf((a[3] + p[3]) * inv * 10000.f) * 1e-4f;
        *(float4*)(orow + d0) = v;
      }
    }
  }
}

extern "C" void kernel_launch(void* const* d_in, const int* in_sizes, int n_in,
                              void* d_out, int out_size, void* d_ws, size_t ws_size,
                              hipStream_t stream) {
  const float* emb = (const float*)d_in[0];
  const float* Wk = (const float*)d_in[1];
  const float* Wq = (const float*)d_in[2];
  const float* Wv = (const float*)d_in[3];
  float* out = (float*)d_out;

  _Float16* ws = (_Float16*)d_ws;
  _Float16* Xp   = ws;                           //  8M halves (packed X)
  _Float16* Wqp  = Xp + (size_t)8192 * 1024;     //  1M (packed Wq rows, k=f)
  _Float16* Wkp  = Wqp + (size_t)1024 * 1024;    //  1M (packed Wk rows, k=f)
  _Float16* Mtp  = Wkp + (size_t)1024 * 1024;    //  1M (packed Wk.Wq^T) — proj B panels 0..63
  _Float16* Wvtp = Mtp + (size_t)1024 * 1024;    //  1M (packed Wv^T)   — proj B panels 64..127
  _Float16* XMp  = Wvtp + (size_t)1024 * 1024;   //  8M (packed XM)
  _Float16* Vtp  = XMp + (size_t)8192 * 1024;    //  8M (packed Vt[d][t])
  _Float16* Ebuf = Vtp + (size_t)8192 * 1024;    // 16M (packed exp-scores E)
  float* lsum    = (float*)(Ebuf + (size_t)16 * 1024 * 1024);  // 8K fp32 row sums

  // zero the row-sum accumulator (ws is poisoned 0xAA before every launch)
  hipMemsetAsync(lsum, 0, 4 * 2048 * sizeof(float), stream);
  prep_kernel<<<1664, 256, 0, stream>>>(emb, Wq, Wk, Wv, Xp, Wqp, Wkp, Wvtp);
  mt_kernel<<<dim3(8, 8), 512, 0, stream>>>(Wkp, Wqp, Mtp);
  proj256_kernel<<<256, 512, 0, stream>>>(Xp, Mtp, XMp, Vtp);
  qke_kernel<<<dim3(136, 4), 256, 0, stream>>>(XMp, Xp, Ebuf, lsum);
  pv_kernel<<<dim3(8, 16, 4), 512, 0, stream>>>(Ebuf, Vtp, lsum, out);
}